// Round 6
// baseline (10122.410 us; speedup 1.0000x reference)
//
#include <hip/hip_runtime.h>

// RecurrentGaussianActor: fused LSTM(64->256) + Linear+ReLU(256) + 2 heads(16).
// One WG per batch row (256 WGs x 512 threads), persistent over T=1000 steps.
//
// Round-7: round-4 structure (proven: no spill, 4554us) with the xg phase
// DISSOLVED INTO THE STEP LOOP. Evidence: VALUBusy 37% -> 63% of each step is
// stall (barrier + LDS latency) with no independent work to fill it; r5
// measured fixed per-step overhead F ~= 37% of step time. Changes:
//  * JIT xg: step t computes xg[t+1] (2 gate rows/thread, 16 dot8) using wih
//    weights streamed from L2 in bursts of 4 h8 (<=16 extra regs in flight,
//    volatile so the compiler cannot hoist all 64 regs). These independent
//    dots + loads fill the step's stall cycles.
//  * xg buffer: 16KB chunk buffer -> 2x2KB double-buffered xg_db.
//  * obs staging for chunk ch+1 folds into step 4 (load+convert+write;
//    xbuf double-buffered). Chunk loop = pure 8-step cadence + layer2 + heads.
//  * step pair-unrolled (x2, not x8) to stay inside the I-cache.
// Spill tell: FETCH >= 1.5 GB means the bursts blew the register budget.

#define NB 256
#define NT 1000
#define NF 64
#define NH 256
#define NG 1024
#define NA 16
#define NTHREADS 512
#define CHUNK 8
#define NCHUNK (NT / CHUNK)
#define HHALF 68  // h2 units per padded h-half: 128 f16 = 64 h2, +4 h2 pad = 272 B

typedef _Float16 h2 __attribute__((ext_vector_type(2)));
typedef _Float16 h4 __attribute__((ext_vector_type(4)));
typedef _Float16 h8 __attribute__((ext_vector_type(8)));
typedef float f4 __attribute__((ext_vector_type(4)));

__device__ __forceinline__ float fdot2(h2 a, h2 b, float c) {
  return __builtin_amdgcn_fdot2(a, b, c, false);
}
__device__ __forceinline__ float fexp2(float x) { return __builtin_amdgcn_exp2f(x); }
__device__ __forceinline__ float frcp(float x) { return __builtin_amdgcn_rcpf(x); }
__device__ __forceinline__ float sigmoidf_(float x) {
  return frcp(1.f + fexp2(-1.4426950408889634f * x));
}
__device__ __forceinline__ float tanhfast(float x) {
  float a = fabsf(x);
  float e = fexp2(-2.8853900817779268f * a);
  float r = (1.f - e) * frcp(1.f + e);
  return __builtin_copysignf(r, x);
}
// dot of 8 f16 elements held in two h8 vectors (4 chained v_dot2_f32_f16)
__device__ __forceinline__ float dot8(h8 x, h8 w, float acc) {
  acc = fdot2(__builtin_shufflevector(x, x, 0, 1), __builtin_shufflevector(w, w, 0, 1), acc);
  acc = fdot2(__builtin_shufflevector(x, x, 2, 3), __builtin_shufflevector(w, w, 2, 3), acc);
  acc = fdot2(__builtin_shufflevector(x, x, 4, 5), __builtin_shufflevector(w, w, 4, 5), acc);
  acc = fdot2(__builtin_shufflevector(x, x, 6, 7), __builtin_shufflevector(w, w, 6, 7), acc);
  return acc;
}
// quad_perm DPP: CTRL=0xB1 -> lanes (1,0,3,2) [xor1 within each quad]
template <int CTRL>
__device__ __forceinline__ float qperm(float x) {
  return __int_as_float(
      __builtin_amdgcn_update_dpp(0, __float_as_int(x), CTRL, 0xF, 0xF, true));
}

// ---- prep: convert/pack weights to f16 pairs in workspace (round-0 verbatim) ----
__global__ void prep_kernel(const float* __restrict__ Wih, const float* __restrict__ Whh,
                            const float* __restrict__ bih, const float* __restrict__ bhh,
                            const float* __restrict__ W2, const float* __restrict__ Wm,
                            const float* __restrict__ Ws,
                            h2* __restrict__ whh, h2* __restrict__ wih,
                            h2* __restrict__ w2w, h2* __restrict__ wmh,
                            float* __restrict__ bg) {
  int i = blockIdx.x * 256 + threadIdx.x;
  if (i < 1024 * 128) {  // W_hh [1024][256] -> [1024][128] pairs
    int j = i >> 7, p = i & 127;
    whh[i] = h2{(_Float16)Whh[j * 256 + 2 * p], (_Float16)Whh[j * 256 + 2 * p + 1]};
  }
  if (i < 1024 * 32) {   // W_ih [1024][64] -> [1024][32] pairs
    int j = i >> 5, p = i & 31;
    wih[i] = h2{(_Float16)Wih[j * 64 + 2 * p], (_Float16)Wih[j * 64 + 2 * p + 1]};
  }
  if (i < 256 * 128) {   // W2 [256][256] -> [256][128] pairs
    int j = i >> 7, p = i & 127;
    w2w[i] = h2{(_Float16)W2[j * 256 + 2 * p], (_Float16)W2[j * 256 + 2 * p + 1]};
  }
  if (i < 32 * 128) {    // Wm rows 0..15, Ws rows 16..31
    int j = i >> 7, p = i & 127;
    float v0, v1;
    if (j < 16) { v0 = Wm[j * 256 + 2 * p]; v1 = Wm[j * 256 + 2 * p + 1]; }
    else        { v0 = Ws[(j - 16) * 256 + 2 * p]; v1 = Ws[(j - 16) * 256 + 2 * p + 1]; }
    wmh[i] = h2{(_Float16)v0, (_Float16)v1};
  }
  if (i < 1024) bg[i] = bih[i] + bhh[i];
}

// ---- main fused persistent kernel: 1 WG per batch row ----
__global__ __launch_bounds__(NTHREADS, 2) void actor_kernel(
    const float* __restrict__ obs,
    const h2* __restrict__ whh, const h2* __restrict__ wih,
    const h2* __restrict__ w2w, const h2* __restrict__ wmh,
    const float* __restrict__ bg, const float* __restrict__ b2,
    const float* __restrict__ bm, const float* __restrict__ bs,
    float* __restrict__ out) {
  __shared__ __align__(16) h8 whh_l[16 * NTHREADS];     // 131072 B
  __shared__ __align__(16) _Float16 xg_db[2][NG];       // 4096 B  dbuf xg [u*4+g]
  __shared__ __align__(16) h2 hbuf[2][2 * HHALF];       // 1088 B  padded dbuf h
  __shared__ __align__(16) h2 hch[CHUNK * NH / 2];      // 4096 B  h history
  __shared__ __align__(16) h2 xbuf[2][CHUNK][NF / 2];   // 2048 B  dbuf obs chunk
  __shared__ __align__(16) h2 x2b[CHUNK * NH / 2];      // 4096 B  layer2 out
  // total 146496 B <= 163840

  const int tid = threadIdx.x;
  const int b = blockIdx.x;
  const int q = tid >> 1;      // hidden unit owned by this lane pair
  const int jhalf = tid & 1;   // h-half [128*jhalf, 128*jhalf+128)
  // xg target slot: thread computes gate rows tid (g=tid>>8) and tid+512
  // (g+2) of unit u=tid&255; xg_db layout [u*4+g].
  const int xgi = ((tid & 255) << 2) + (tid >> 8);

  // ---- register-resident W_hh: h8s 4..15 of own half, 4 gate rows of q ----
  // 48 x h8 = 192 regs (proven footprint). VOLATILE: no remat in step loop.
  h8 wreg[48];
  {
    const volatile h8* vw = (const volatile h8*)whh;  // row stride = 32 h8
#pragma unroll
    for (int g = 0; g < 4; g++)
#pragma unroll
      for (int jj = 0; jj < 12; jj++)
        wreg[g * 12 + jj] = vw[(g * 256 + q) * 32 + jhalf * 16 + 4 + jj];
  }
  // ---- LDS-resident W_hh: h8s 0..3 of own half, column (g*4+s), idx tid ----
  {
    const h8* whh8 = (const h8*)whh;
#pragma unroll
    for (int g = 0; g < 4; g++)
#pragma unroll
      for (int s = 0; s < 4; s++)
        whh_l[(g * 4 + s) * NTHREADS + tid] = whh8[(g * 256 + q) * 32 + jhalf * 16 + s];
  }
  if (tid < 2 * HHALF) hbuf[0][tid] = h2{(_Float16)0.f, (_Float16)0.f};
  float c_state = 0.f;  // replicated across the lane pair
  const float bg0 = bg[tid], bg1 = bg[tid + 512];
  const float b2v = b2[tid & 255];
  const int oh = tid & 31;
  const float hbv = (oh < NA) ? bm[oh] : bs[oh - NA];
  __syncthreads();

  const float* obs_b = obs + (size_t)b * NT * NF;
  float* out_means = out;
  float* out_stds = out + (size_t)NB * NT * NA;
  const volatile h8* vwih = (const volatile h8*)wih;  // streamed per step (L2)

  // ---- prologue: stage obs chunk 0 and xg for t=0 ----
  if (tid < 128) {
    int tq = tid >> 4, fq = tid & 15;
    f4 v = *(const f4*)(obs_b + (size_t)tq * NF + fq * 4);
    xbuf[0][tq][fq * 2] = h2{(_Float16)v[0], (_Float16)v[1]};
    xbuf[0][tq][fq * 2 + 1] = h2{(_Float16)v[2], (_Float16)v[3]};
  }
  __syncthreads();
  {
    float xga = bg0, xgb = bg1;
#pragma unroll
    for (int j = 0; j < 8; j++) {
      h8 wa = vwih[tid * 8 + j];
      h8 wb = vwih[(tid + 512) * 8 + j];
      h8 xv = *(const h8*)&xbuf[0][0][j * 4];
      xga = dot8(xv, wa, xga);
      xgb = dot8(xv, wb, xgb);
    }
    xg_db[0][xgi] = (_Float16)xga;
    xg_db[0][xgi + 2] = (_Float16)xgb;
  }
  __syncthreads();

  for (int ch = 0; ch < NCHUNK; ++ch) {
    const int cb = ch & 1;
    const int t0 = ch * CHUNK;
    const int chn = (ch + 1 < NCHUNK) ? ch + 1 : ch;  // clamp for last chunk

    // ---- 8 recurrent LSTM steps, ONE barrier each; xg[t+1] computed JIT ----
    for (int th = 0; th < CHUNK / 2; th++) {
#pragma unroll
      for (int te = 0; te < 2; te++) {
        const int t = th * 2 + te;
        const _Float16* hb = (const _Float16*)&hbuf[te][jhalf * HHALF];
        // obs source for xg[t+1]: this chunk's t+1, or next chunk's t=0
        const _Float16* xsrc = (t < CHUNK - 1)
                                   ? (const _Float16*)&xbuf[cb][t + 1][0]
                                   : (const _Float16*)&xbuf[cb ^ 1][0][0];
        // burst 0: wih row tid, F-chunks 0..3 (16 regs in flight)
        h8 iw0 = vwih[tid * 8 + 0], iw1 = vwih[tid * 8 + 1],
           iw2 = vwih[tid * 8 + 2], iw3 = vwih[tid * 8 + 3];
        float p0 = 0.f, p1 = 0.f, p2 = 0.f, p3 = 0.f;
#pragma unroll
        for (int s = 0; s < 4; s++) {
          h8 hv = *(const h8*)(hb + s * 8);
          p0 = dot8(hv, whh_l[(0 * 4 + s) * NTHREADS + tid], p0);
          p1 = dot8(hv, whh_l[(1 * 4 + s) * NTHREADS + tid], p1);
          p2 = dot8(hv, whh_l[(2 * 4 + s) * NTHREADS + tid], p2);
          p3 = dot8(hv, whh_l[(3 * 4 + s) * NTHREADS + tid], p3);
        }
        float xga = bg0;
        xga = dot8(*(const h8*)(xsrc + 0), iw0, xga);
        xga = dot8(*(const h8*)(xsrc + 8), iw1, xga);
        xga = dot8(*(const h8*)(xsrc + 16), iw2, xga);
        xga = dot8(*(const h8*)(xsrc + 24), iw3, xga);
        // burst 1: wih row tid, F-chunks 4..7
        iw0 = vwih[tid * 8 + 4]; iw1 = vwih[tid * 8 + 5];
        iw2 = vwih[tid * 8 + 6]; iw3 = vwih[tid * 8 + 7];
#pragma unroll
        for (int jj = 0; jj < 6; jj++) {
          h8 hv = *(const h8*)(hb + 32 + jj * 8);
          p0 = dot8(hv, wreg[jj], p0);
          p1 = dot8(hv, wreg[12 + jj], p1);
          p2 = dot8(hv, wreg[24 + jj], p2);
          p3 = dot8(hv, wreg[36 + jj], p3);
        }
        xga = dot8(*(const h8*)(xsrc + 32), iw0, xga);
        xga = dot8(*(const h8*)(xsrc + 40), iw1, xga);
        xga = dot8(*(const h8*)(xsrc + 48), iw2, xga);
        xga = dot8(*(const h8*)(xsrc + 56), iw3, xga);
        xg_db[te ^ 1][xgi] = (_Float16)xga;
        // burst 2: wih row tid+512, F-chunks 0..3
        iw0 = vwih[(tid + 512) * 8 + 0]; iw1 = vwih[(tid + 512) * 8 + 1];
        iw2 = vwih[(tid + 512) * 8 + 2]; iw3 = vwih[(tid + 512) * 8 + 3];
#pragma unroll
        for (int jj = 6; jj < 12; jj++) {
          h8 hv = *(const h8*)(hb + 32 + jj * 8);
          p0 = dot8(hv, wreg[jj], p0);
          p1 = dot8(hv, wreg[12 + jj], p1);
          p2 = dot8(hv, wreg[24 + jj], p2);
          p3 = dot8(hv, wreg[36 + jj], p3);
        }
        float xgb = bg1;
        xgb = dot8(*(const h8*)(xsrc + 0), iw0, xgb);
        xgb = dot8(*(const h8*)(xsrc + 8), iw1, xgb);
        xgb = dot8(*(const h8*)(xsrc + 16), iw2, xgb);
        xgb = dot8(*(const h8*)(xsrc + 24), iw3, xgb);
        // burst 3: wih row tid+512, F-chunks 4..7
        iw0 = vwih[(tid + 512) * 8 + 4]; iw1 = vwih[(tid + 512) * 8 + 5];
        iw2 = vwih[(tid + 512) * 8 + 6]; iw3 = vwih[(tid + 512) * 8 + 7];
        // xor-1 DPP butterfly + gate math (fills burst-3 latency)
        p0 += qperm<0xB1>(p0);
        p1 += qperm<0xB1>(p1);
        p2 += qperm<0xB1>(p2);
        p3 += qperm<0xB1>(p3);
        h4 xg4 = *(const h4*)&xg_db[te][q * 4];
        float gi = sigmoidf_(p0 + (float)xg4[0]);
        float gf = sigmoidf_(p1 + (float)xg4[1]);
        float gg = tanhfast(p2 + (float)xg4[2]);
        float go = sigmoidf_(p3 + (float)xg4[3]);
        c_state = gf * c_state + gi * gg;
        float hval = go * tanhfast(c_state);
        if (jhalf == 0) {  // one lane per unit publishes
          _Float16 hh = (_Float16)hval;
          ((_Float16*)&hbuf[te ^ 1][(q >> 7) * HHALF])[q & 127] = hh;
          ((_Float16*)hch)[t * NH + q] = hh;  // history for layer2
        }
        xgb = dot8(*(const h8*)(xsrc + 32), iw0, xgb);
        xgb = dot8(*(const h8*)(xsrc + 40), iw1, xgb);
        xgb = dot8(*(const h8*)(xsrc + 48), iw2, xgb);
        xgb = dot8(*(const h8*)(xsrc + 56), iw3, xgb);
        xg_db[te ^ 1][xgi + 2] = (_Float16)xgb;
        // step 4: stage next chunk's obs into the other xbuf
        if (te == 0 && th == 2 && tid < 128) {
          int tq = tid >> 4, fq = tid & 15;
          f4 v = *(const f4*)(obs_b + ((size_t)chn * CHUNK + tq) * NF + fq * 4);
          xbuf[cb ^ 1][tq][fq * 2] = h2{(_Float16)v[0], (_Float16)v[1]};
          xbuf[cb ^ 1][tq][fq * 2 + 1] = h2{(_Float16)v[2], (_Float16)v[3]};
        }
        __syncthreads();  // h(t+1), xg(t+1) visible
      }
    }

    // ---- layer2: x2 = relu(h @ W2^T + b2) (round-0 verbatim) ----
    {
      const int o = tid & 255;
      const int tb = (tid >> 8) * 4;  // 4 timesteps per thread
      float acc[4] = {b2v, b2v, b2v, b2v};
      const h8* wrow = (const h8*)w2w + o * 32;
#pragma unroll 2
      for (int c = 0; c < 8; c++) {
        h8 w[4];
#pragma unroll
        for (int qq = 0; qq < 4; qq++) w[qq] = wrow[c * 4 + qq];
#pragma unroll
        for (int tt = 0; tt < 4; tt++) {
#pragma unroll
          for (int qq = 0; qq < 4; qq++) {
            h8 xv = *(const h8*)&hch[(tb + tt) * 128 + c * 16 + qq * 4];
            acc[tt] = dot8(xv, w[qq], acc[tt]);
          }
        }
      }
#pragma unroll
      for (int tt = 0; tt < 4; tt++)
        ((_Float16*)x2b)[(tb + tt) * NH + o] = (_Float16)fmaxf(acc[tt], 0.f);
    }
    __syncthreads();

    // ---- heads: 32 outputs x 8 timesteps on first 256 threads (verbatim) ----
    if (tid < 256) {
      const int tt = tid >> 5;
      const h8* wrow = (const h8*)wmh + oh * 32;
      float acc = 0.f;
#pragma unroll 4
      for (int c = 0; c < 32; c++) {
        h8 xv = *(const h8*)&x2b[tt * 128 + c * 4];
        acc = dot8(xv, wrow[c], acc);
      }
      acc += hbv;
      const size_t idx = ((size_t)b * NT + (t0 + tt)) * NA + (oh & 15);
      if (oh < NA) {
        out_means[idx] = acc;
      } else {
        float ls = fminf(fmaxf(acc, -20.f), 2.f);
        out_stds[idx] = fexp2(1.4426950408889634f * ls);
      }
    }
    // no trailing barrier: next chunk's steps touch hbuf/hch/xg_db only after
    // the step-0 barrier, and heads read only x2b (safe vs step-0's writes).
  }
}

extern "C" void kernel_launch(void* const* d_in, const int* in_sizes, int n_in,
                              void* d_out, int out_size, void* d_ws, size_t ws_size,
                              hipStream_t stream) {
  const float* obs = (const float*)d_in[0];
  const float* Wih = (const float*)d_in[1];
  const float* Whh = (const float*)d_in[2];
  const float* bih = (const float*)d_in[3];
  const float* bhh = (const float*)d_in[4];
  const float* W2 = (const float*)d_in[5];
  const float* b2 = (const float*)d_in[6];
  const float* Wm = (const float*)d_in[7];
  const float* bm = (const float*)d_in[8];
  const float* Ws = (const float*)d_in[9];
  const float* bs = (const float*)d_in[10];

  char* ws = (char*)d_ws;
  h2* whh = (h2*)(ws + 0);            // 512 KB
  h2* wih = (h2*)(ws + 524288);       // 128 KB
  h2* w2w = (h2*)(ws + 655360);       // 128 KB
  h2* wmh = (h2*)(ws + 786432);       // 16 KB
  float* bg = (float*)(ws + 802816);  // 4 KB

  prep_kernel<<<512, 256, 0, stream>>>(Wih, Whh, bih, bhh, W2, Wm, Ws,
                                       whh, wih, w2w, wmh, bg);
  actor_kernel<<<NB, NTHREADS, 0, stream>>>(obs, whh, wih, w2w, wmh, bg, b2, bm,
                                            bs, (float*)d_out);
}

// Round 7
// 5903.020 us; speedup vs baseline: 1.7148x; 1.7148x over previous
//
#include <hip/hip_runtime.h>

// RecurrentGaussianActor: fused LSTM(64->256) + Linear+ReLU(256) + 2 heads(16).
// One WG per batch row (256 WGs x 512 threads), persistent over T=1000 steps.
//
// Round-8: r4 structure with the ENTIRE per-thread W_hh slice in registers.
// Evidence trail: issue floor ~0.6ms vs measured 4.5ms -> step loop is
// latency-bound at 2 waves/SIMD; r4 proved hbuf reads + barrier count are NOT
// the exposed latency; r6 proved adding latency to the step body is fatal.
// Remaining per-step LDS dependence: 16 whh_l weight b128 reads/thread --
// re-reads of CONSTANT weights, interleaved with the dot chain (fresh lgkmcnt
// dep each + ~1500 cyc/step of LDS pipe + they starve the compiler of regs to
// prefetch hv). Fix:
//  * wreg[64] = 256 regs/thread holds all 4 gate rows x own h-half (volatile
//    loads once; no remat). whh_l DELETED -> LDS 158KB -> 27KB.
//  * Step loop LDS deps: 16 independent hv b128 reads + 1 xg b64. With ~100
//    free arch VGPRs the compiler can hoist all 16 reads -> one wait/step.
//  * Everything else r4-verbatim: dbuf padded hbuf (272B halves), xor-1 DPP
//    butterfly, 1 barrier/step, xg [t][u][4g] phase, layer2/heads phases.
// Tells: FETCH>=1GB = spill (revert); LDS_Block_Size~27KB confirms layout.

#define NB 256
#define NT 1000
#define NF 64
#define NH 256
#define NG 1024
#define NA 16
#define NTHREADS 512
#define CHUNK 8
#define NCHUNK (NT / CHUNK)
#define HHALF 68  // h2 units per padded h-half: 128 f16 = 64 h2, +4 h2 pad = 272 B

typedef _Float16 h2 __attribute__((ext_vector_type(2)));
typedef _Float16 h4 __attribute__((ext_vector_type(4)));
typedef _Float16 h8 __attribute__((ext_vector_type(8)));
typedef float f4 __attribute__((ext_vector_type(4)));

__device__ __forceinline__ float fdot2(h2 a, h2 b, float c) {
  return __builtin_amdgcn_fdot2(a, b, c, false);
}
__device__ __forceinline__ float fexp2(float x) { return __builtin_amdgcn_exp2f(x); }
__device__ __forceinline__ float frcp(float x) { return __builtin_amdgcn_rcpf(x); }
__device__ __forceinline__ float sigmoidf_(float x) {
  return frcp(1.f + fexp2(-1.4426950408889634f * x));
}
__device__ __forceinline__ float tanhfast(float x) {
  float a = fabsf(x);
  float e = fexp2(-2.8853900817779268f * a);
  float r = (1.f - e) * frcp(1.f + e);
  return __builtin_copysignf(r, x);
}
// dot of 8 f16 elements held in two h8 vectors (4 chained v_dot2_f32_f16)
__device__ __forceinline__ float dot8(h8 x, h8 w, float acc) {
  acc = fdot2(__builtin_shufflevector(x, x, 0, 1), __builtin_shufflevector(w, w, 0, 1), acc);
  acc = fdot2(__builtin_shufflevector(x, x, 2, 3), __builtin_shufflevector(w, w, 2, 3), acc);
  acc = fdot2(__builtin_shufflevector(x, x, 4, 5), __builtin_shufflevector(w, w, 4, 5), acc);
  acc = fdot2(__builtin_shufflevector(x, x, 6, 7), __builtin_shufflevector(w, w, 6, 7), acc);
  return acc;
}
// quad_perm DPP: CTRL=0xB1 -> lanes (1,0,3,2) [xor1 within each quad]
template <int CTRL>
__device__ __forceinline__ float qperm(float x) {
  return __int_as_float(
      __builtin_amdgcn_update_dpp(0, __float_as_int(x), CTRL, 0xF, 0xF, true));
}

// ---- prep: convert/pack weights to f16 pairs in workspace (round-0 verbatim) ----
__global__ void prep_kernel(const float* __restrict__ Wih, const float* __restrict__ Whh,
                            const float* __restrict__ bih, const float* __restrict__ bhh,
                            const float* __restrict__ W2, const float* __restrict__ Wm,
                            const float* __restrict__ Ws,
                            h2* __restrict__ whh, h2* __restrict__ wih,
                            h2* __restrict__ w2w, h2* __restrict__ wmh,
                            float* __restrict__ bg) {
  int i = blockIdx.x * 256 + threadIdx.x;
  if (i < 1024 * 128) {  // W_hh [1024][256] -> [1024][128] pairs
    int j = i >> 7, p = i & 127;
    whh[i] = h2{(_Float16)Whh[j * 256 + 2 * p], (_Float16)Whh[j * 256 + 2 * p + 1]};
  }
  if (i < 1024 * 32) {   // W_ih [1024][64] -> [1024][32] pairs
    int j = i >> 5, p = i & 31;
    wih[i] = h2{(_Float16)Wih[j * 64 + 2 * p], (_Float16)Wih[j * 64 + 2 * p + 1]};
  }
  if (i < 256 * 128) {   // W2 [256][256] -> [256][128] pairs
    int j = i >> 7, p = i & 127;
    w2w[i] = h2{(_Float16)W2[j * 256 + 2 * p], (_Float16)W2[j * 256 + 2 * p + 1]};
  }
  if (i < 32 * 128) {    // Wm rows 0..15, Ws rows 16..31
    int j = i >> 7, p = i & 127;
    float v0, v1;
    if (j < 16) { v0 = Wm[j * 256 + 2 * p]; v1 = Wm[j * 256 + 2 * p + 1]; }
    else        { v0 = Ws[(j - 16) * 256 + 2 * p]; v1 = Ws[(j - 16) * 256 + 2 * p + 1]; }
    wmh[i] = h2{(_Float16)v0, (_Float16)v1};
  }
  if (i < 1024) bg[i] = bih[i] + bhh[i];
}

// ---- main fused persistent kernel: 1 WG per batch row ----
__global__ __launch_bounds__(NTHREADS, 2) void actor_kernel(
    const float* __restrict__ obs,
    const h2* __restrict__ whh, const h2* __restrict__ wih,
    const h2* __restrict__ w2w, const h2* __restrict__ wmh,
    const float* __restrict__ bg, const float* __restrict__ b2,
    const float* __restrict__ bm, const float* __restrict__ bs,
    float* __restrict__ out) {
  __shared__ __align__(16) _Float16 xg_l[CHUNK * NG];   // 16384 B [t][u][4g]
  __shared__ __align__(16) h2 hbuf[2][2 * HHALF];       // 1088 B padded dbuf h
  __shared__ __align__(16) h2 hch[CHUNK * NH / 2];      // 4096 B  h history
  __shared__ __align__(16) h2 xbuf[CHUNK * NF / 2];     // 1024 B  obs chunk
  __shared__ __align__(16) h2 x2b[CHUNK * NH / 2];      // 4096 B  layer2 out
  // total 26688 B -- whh_l is GONE

  const int tid = threadIdx.x;
  const int b = blockIdx.x;
  const int q = tid >> 1;      // hidden unit owned by this lane pair
  const int jhalf = tid & 1;   // h-half [128*jhalf, 128*jhalf+128)

  // ---- register-resident W_hh: ALL 16 h8s of own half x 4 gate rows of q ----
  // 64 x h8 = 256 regs. VOLATILE: no remat-from-global inside the step loop.
  h8 wreg[64];
  {
    const volatile h8* vw = (const volatile h8*)whh;  // row stride = 32 h8
#pragma unroll
    for (int g = 0; g < 4; g++)
#pragma unroll
      for (int jj = 0; jj < 16; jj++)
        wreg[g * 16 + jj] = vw[(g * 256 + q) * 32 + jhalf * 16 + jj];
  }
  if (tid < 2 * HHALF) hbuf[0][tid] = h2{(_Float16)0.f, (_Float16)0.f};
  float c_state = 0.f;  // replicated across the lane pair
  const float bg0 = bg[tid], bg1 = bg[tid + 512];  // xg bias rows tid, tid+512
  const float b2v = b2[tid & 255];
  const int oh = tid & 31;
  const float hbv = (oh < NA) ? bm[oh] : bs[oh - NA];
  __syncthreads();

  const float* obs_b = obs + (size_t)b * NT * NF;
  float* out_means = out;
  float* out_stds = out + (size_t)NB * NT * NA;

  for (int ch = 0; ch < NCHUNK; ++ch) {
    const int t0 = ch * CHUNK;

    // ---- stage obs chunk -> f16 pairs in LDS (round-0 verbatim) ----
    if (tid < 128) {
      int t = tid >> 4, fq = tid & 15;
      f4 v = *(const f4*)(obs_b + (size_t)(t0 + t) * NF + fq * 4);
      xbuf[t * 32 + fq * 2] = h2{(_Float16)v[0], (_Float16)v[1]};
      xbuf[t * 32 + fq * 2 + 1] = h2{(_Float16)v[2], (_Float16)v[3]};
    }
    __syncthreads();

    // ---- xg for rows tid and tid+512 (round-0 math, [t][u][4g] store) ----
#pragma unroll
    for (int rr = 0; rr < 2; ++rr) {
      const int row = tid + rr * 512;
      const float bias = rr ? bg1 : bg0;
      float acc[CHUNK];
#pragma unroll
      for (int t = 0; t < CHUNK; t++) acc[t] = bias;
      const h8* wrow = (const h8*)wih + row * 8;
#pragma unroll
      for (int jh = 0; jh < 2; jh++) {
        h8 w[4];
#pragma unroll
        for (int qq = 0; qq < 4; qq++) w[qq] = wrow[jh * 4 + qq];
#pragma unroll
        for (int t = 0; t < CHUNK; t++) {
#pragma unroll
          for (int qq = 0; qq < 4; qq++) {
            h8 xv = *(const h8*)&xbuf[t * 32 + jh * 16 + qq * 4];
            acc[t] = dot8(xv, w[qq], acc[t]);
          }
        }
      }
      const int g = row >> 8, uu = row & 255;
#pragma unroll
      for (int t = 0; t < CHUNK; t++)
        xg_l[(t * 256 + uu) * 4 + g] = (_Float16)acc[t];
    }
    __syncthreads();

    // ---- 8 recurrent LSTM steps, ONE barrier each ----
    // Only LDS deps per step: 16 INDEPENDENT hv b128 reads + 1 xg b64; all
    // weights come from wreg. Compiler has ~100 free arch regs to hoist reads.
    for (int t = 0; t < CHUNK; t++) {
      const _Float16* hb = (const _Float16*)&hbuf[t & 1][jhalf * HHALF];
      h4 xg4 = *(const h4*)&xg_l[(t * 256 + q) * 4];  // b64 broadcast
      float p0 = 0.f, p1 = 0.f, p2 = 0.f, p3 = 0.f;
#pragma unroll
      for (int jj = 0; jj < 16; jj++) {
        h8 hv = *(const h8*)(hb + jj * 8);
        p0 = dot8(hv, wreg[jj], p0);
        p1 = dot8(hv, wreg[16 + jj], p1);
        p2 = dot8(hv, wreg[32 + jj], p2);
        p3 = dot8(hv, wreg[48 + jj], p3);
      }
      // xor-1 DPP butterfly: both lanes of the pair get all 4 full sums.
      p0 += qperm<0xB1>(p0);
      p1 += qperm<0xB1>(p1);
      p2 += qperm<0xB1>(p2);
      p3 += qperm<0xB1>(p3);
      float gi = sigmoidf_(p0 + (float)xg4[0]);
      float gf = sigmoidf_(p1 + (float)xg4[1]);
      float gg = tanhfast(p2 + (float)xg4[2]);
      float go = sigmoidf_(p3 + (float)xg4[3]);
      c_state = gf * c_state + gi * gg;
      float hval = go * tanhfast(c_state);
      if (jhalf == 0) {  // one lane per unit publishes
        _Float16 hh = (_Float16)hval;
        ((_Float16*)&hbuf[(t + 1) & 1][(q >> 7) * HHALF])[q & 127] = hh;
        ((_Float16*)hch)[t * NH + q] = hh;  // history for layer2
      }
      __syncthreads();  // h(t+1) visible; hbuf[t&1] free for step t+2's write
    }

    // ---- layer2: x2 = relu(h @ W2^T + b2) (round-0 verbatim) ----
    {
      const int o = tid & 255;
      const int tb = (tid >> 8) * 4;  // 4 timesteps per thread
      float acc[4] = {b2v, b2v, b2v, b2v};
      const h8* wrow = (const h8*)w2w + o * 32;
#pragma unroll 2
      for (int c = 0; c < 8; c++) {
        h8 w[4];
#pragma unroll
        for (int qq = 0; qq < 4; qq++) w[qq] = wrow[c * 4 + qq];
#pragma unroll
        for (int tt = 0; tt < 4; tt++) {
#pragma unroll
          for (int qq = 0; qq < 4; qq++) {
            h8 xv = *(const h8*)&hch[(tb + tt) * 128 + c * 16 + qq * 4];
            acc[tt] = dot8(xv, w[qq], acc[tt]);
          }
        }
      }
#pragma unroll
      for (int tt = 0; tt < 4; tt++)
        ((_Float16*)x2b)[(tb + tt) * NH + o] = (_Float16)fmaxf(acc[tt], 0.f);
    }
    __syncthreads();

    // ---- heads: 32 outputs x 8 timesteps on first 256 threads (verbatim) ----
    if (tid < 256) {
      const int tt = tid >> 5;
      const h8* wrow = (const h8*)wmh + oh * 32;
      float acc = 0.f;
#pragma unroll 4
      for (int c = 0; c < 32; c++) {
        h8 xv = *(const h8*)&x2b[tt * 128 + c * 4];
        acc = dot8(xv, wrow[c], acc);
      }
      acc += hbv;
      const size_t idx = ((size_t)b * NT + (t0 + tt)) * NA + (oh & 15);
      if (oh < NA) {
        out_means[idx] = acc;
      } else {
        float ls = fminf(fmaxf(acc, -20.f), 2.f);
        out_stds[idx] = fexp2(1.4426950408889634f * ls);
      }
    }
    // no trailing barrier: next chunk's first write to x2b (its layer2) is
    // separated from these reads by the staging/xg/step barriers.
  }
}

extern "C" void kernel_launch(void* const* d_in, const int* in_sizes, int n_in,
                              void* d_out, int out_size, void* d_ws, size_t ws_size,
                              hipStream_t stream) {
  const float* obs = (const float*)d_in[0];
  const float* Wih = (const float*)d_in[1];
  const float* Whh = (const float*)d_in[2];
  const float* bih = (const float*)d_in[3];
  const float* bhh = (const float*)d_in[4];
  const float* W2 = (const float*)d_in[5];
  const float* b2 = (const float*)d_in[6];
  const float* Wm = (const float*)d_in[7];
  const float* bm = (const float*)d_in[8];
  const float* Ws = (const float*)d_in[9];
  const float* bs = (const float*)d_in[10];

  char* ws = (char*)d_ws;
  h2* whh = (h2*)(ws + 0);            // 512 KB
  h2* wih = (h2*)(ws + 524288);       // 128 KB
  h2* w2w = (h2*)(ws + 655360);       // 128 KB
  h2* wmh = (h2*)(ws + 786432);       // 16 KB
  float* bg = (float*)(ws + 802816);  // 4 KB

  prep_kernel<<<512, 256, 0, stream>>>(Wih, Whh, bih, bhh, W2, Wm, Ws,
                                       whh, wih, w2w, wmh, bg);
  actor_kernel<<<NB, NTHREADS, 0, stream>>>(obs, whh, wih, w2w, wmh, bg, b2, bm,
                                            bs, (float*)d_out);
}

// Round 8
// 4300.302 us; speedup vs baseline: 2.3539x; 1.3727x over previous
//
#include <hip/hip_runtime.h>

// RecurrentGaussianActor: fused LSTM(64->256) + Linear+ReLU(256) + 2 heads(16).
// One WG per batch row (256 WGs x 512 threads), persistent over T=1000 steps.
//
// Round-9: r4 (equal-best, 4554us, no-spill) with the SAME numerics/layout/
// register footprint but the two hot loops rewritten as explicit software
// pipelines. Evidence: r0~r4 despite -33% LDS reads & -50% barriers -> the
// stall is read->use ADJACENCY (every ds_read written inline as a dot
// operand exposes ~120cy LDS latency; 2 waves/SIMD can't fill it; compiler
// can't hoist: 0 spare arch regs with 192 AGPR-resident weights). r7 proved
// (3rd time) >192 persistent values always spills -> keep 48xh8 exactly.
// Changes:
//  * Step loop: every ds_read issued >=1 dot-group (~128 issue cyc) before
//    first use. hv in rotating groups of 4 (a0-3/b0-3); LDS weights
//    double-buffered per-s (u0-3/v0-3); weight bases split (wlA gates 0-1,
//    wlB gates 2-3) so all 16 w-reads use compile-time offset: immediates
//    (no per-read addr math). Live prefetch regs ~70 of 128 arch.
//  * layer2: W2 row double-buffered across the c-loop.
// Everything else r4-verbatim. Tells: FETCH>1.5GB = prefetch broke the reg
// budget (revert); neutral result = stall is structural, not latency.

#define NB 256
#define NT 1000
#define NF 64
#define NH 256
#define NG 1024
#define NA 16
#define NTHREADS 512
#define CHUNK 8
#define NCHUNK (NT / CHUNK)
#define HHALF 68  // h2 units per padded h-half: 128 f16 = 64 h2, +4 h2 pad = 272 B

typedef _Float16 h2 __attribute__((ext_vector_type(2)));
typedef _Float16 h4 __attribute__((ext_vector_type(4)));
typedef _Float16 h8 __attribute__((ext_vector_type(8)));
typedef float f4 __attribute__((ext_vector_type(4)));

__device__ __forceinline__ float fdot2(h2 a, h2 b, float c) {
  return __builtin_amdgcn_fdot2(a, b, c, false);
}
__device__ __forceinline__ float fexp2(float x) { return __builtin_amdgcn_exp2f(x); }
__device__ __forceinline__ float frcp(float x) { return __builtin_amdgcn_rcpf(x); }
__device__ __forceinline__ float sigmoidf_(float x) {
  return frcp(1.f + fexp2(-1.4426950408889634f * x));
}
__device__ __forceinline__ float tanhfast(float x) {
  float a = fabsf(x);
  float e = fexp2(-2.8853900817779268f * a);
  float r = (1.f - e) * frcp(1.f + e);
  return __builtin_copysignf(r, x);
}
// dot of 8 f16 elements held in two h8 vectors (4 chained v_dot2_f32_f16)
__device__ __forceinline__ float dot8(h8 x, h8 w, float acc) {
  acc = fdot2(__builtin_shufflevector(x, x, 0, 1), __builtin_shufflevector(w, w, 0, 1), acc);
  acc = fdot2(__builtin_shufflevector(x, x, 2, 3), __builtin_shufflevector(w, w, 2, 3), acc);
  acc = fdot2(__builtin_shufflevector(x, x, 4, 5), __builtin_shufflevector(w, w, 4, 5), acc);
  acc = fdot2(__builtin_shufflevector(x, x, 6, 7), __builtin_shufflevector(w, w, 6, 7), acc);
  return acc;
}
// quad_perm DPP: CTRL=0xB1 -> lanes (1,0,3,2) [xor1 within each quad]
template <int CTRL>
__device__ __forceinline__ float qperm(float x) {
  return __int_as_float(
      __builtin_amdgcn_update_dpp(0, __float_as_int(x), CTRL, 0xF, 0xF, true));
}

// ---- prep: convert/pack weights to f16 pairs in workspace (round-0 verbatim) ----
__global__ void prep_kernel(const float* __restrict__ Wih, const float* __restrict__ Whh,
                            const float* __restrict__ bih, const float* __restrict__ bhh,
                            const float* __restrict__ W2, const float* __restrict__ Wm,
                            const float* __restrict__ Ws,
                            h2* __restrict__ whh, h2* __restrict__ wih,
                            h2* __restrict__ w2w, h2* __restrict__ wmh,
                            float* __restrict__ bg) {
  int i = blockIdx.x * 256 + threadIdx.x;
  if (i < 1024 * 128) {  // W_hh [1024][256] -> [1024][128] pairs
    int j = i >> 7, p = i & 127;
    whh[i] = h2{(_Float16)Whh[j * 256 + 2 * p], (_Float16)Whh[j * 256 + 2 * p + 1]};
  }
  if (i < 1024 * 32) {   // W_ih [1024][64] -> [1024][32] pairs
    int j = i >> 5, p = i & 31;
    wih[i] = h2{(_Float16)Wih[j * 64 + 2 * p], (_Float16)Wih[j * 64 + 2 * p + 1]};
  }
  if (i < 256 * 128) {   // W2 [256][256] -> [256][128] pairs
    int j = i >> 7, p = i & 127;
    w2w[i] = h2{(_Float16)W2[j * 256 + 2 * p], (_Float16)W2[j * 256 + 2 * p + 1]};
  }
  if (i < 32 * 128) {    // Wm rows 0..15, Ws rows 16..31
    int j = i >> 7, p = i & 127;
    float v0, v1;
    if (j < 16) { v0 = Wm[j * 256 + 2 * p]; v1 = Wm[j * 256 + 2 * p + 1]; }
    else        { v0 = Ws[(j - 16) * 256 + 2 * p]; v1 = Ws[(j - 16) * 256 + 2 * p + 1]; }
    wmh[i] = h2{(_Float16)v0, (_Float16)v1};
  }
  if (i < 1024) bg[i] = bih[i] + bhh[i];
}

// ---- main fused persistent kernel: 1 WG per batch row ----
__global__ __launch_bounds__(NTHREADS, 2) void actor_kernel(
    const float* __restrict__ obs,
    const h2* __restrict__ whh, const h2* __restrict__ wih,
    const h2* __restrict__ w2w, const h2* __restrict__ wmh,
    const float* __restrict__ bg, const float* __restrict__ b2,
    const float* __restrict__ bm, const float* __restrict__ bs,
    float* __restrict__ out) {
  // W_hh h8-slices 0..3 of this thread's (4 rows x own h-half): 16 columns
  // of [512] h8; reads lane-linear b128 -> conflict-free (r4 layout).
  __shared__ __align__(16) h8 whh_l[16 * NTHREADS];        // 131072 B
  __shared__ __align__(16) _Float16 xg_l[CHUNK * NG];      // 16384 B [t][u][4g]
  __shared__ __align__(16) h2 hbuf[2][2 * HHALF];          // 1088 B padded dbuf h
  __shared__ __align__(16) h2 hch[CHUNK * NH / 2];         // 4096 B  h history
  __shared__ __align__(16) h2 xbuf[CHUNK * NF / 2];        // 1024 B  obs chunk
  __shared__ __align__(16) h2 x2b[CHUNK * NH / 2];         // 4096 B  layer2 out
  // total 157760 B <= 163840

  const int tid = threadIdx.x;
  const int b = blockIdx.x;
  const int q = tid >> 1;      // hidden unit owned by this lane pair
  const int jhalf = tid & 1;   // h-half [128*jhalf, 128*jhalf+128)

  // ---- register-resident W_hh: h8s 4..15 of own half, 4 gate rows of q ----
  // 48 x h8 = 192 regs (THE proven stable footprint; r1/r3/r7 all spill past
  // it). VOLATILE: no remat-from-global inside the step loop.
  h8 wreg[48];
  {
    const volatile h8* vw = (const volatile h8*)whh;  // row stride = 32 h8
#pragma unroll
    for (int g = 0; g < 4; g++)
#pragma unroll
      for (int jj = 0; jj < 12; jj++)
        wreg[g * 12 + jj] = vw[(g * 256 + q) * 32 + jhalf * 16 + 4 + jj];
  }
  // ---- LDS-resident W_hh: h8s 0..3 of own half, column (g*4+s), idx tid ----
  {
    const h8* whh8 = (const h8*)whh;
#pragma unroll
    for (int g = 0; g < 4; g++)
#pragma unroll
      for (int s = 0; s < 4; s++)
        whh_l[(g * 4 + s) * NTHREADS + tid] = whh8[(g * 256 + q) * 32 + jhalf * 16 + s];
  }
  if (tid < 2 * HHALF) hbuf[0][tid] = h2{(_Float16)0.f, (_Float16)0.f};
  float c_state = 0.f;  // replicated across the lane pair
  const float bg0 = bg[tid], bg1 = bg[tid + 512];  // xg bias rows tid, tid+512
  const float b2v = b2[tid & 255];
  const int oh = tid & 31;
  const float hbv = (oh < NA) ? bm[oh] : bs[oh - NA];
  __syncthreads();

  const float* obs_b = obs + (size_t)b * NT * NF;
  float* out_means = out;
  float* out_stds = out + (size_t)NB * NT * NA;
  // weight base pointers: all 16 step-loop w-reads become ds_read with
  // compile-time offset: immediates (byte offsets <= 57344 < 64K).
  const h8* wlA = whh_l + tid;                 // gates 0,1: elem (g*4+s)*512
  const h8* wlB = whh_l + 8 * NTHREADS + tid;  // gates 2,3

  for (int ch = 0; ch < NCHUNK; ++ch) {
    const int t0 = ch * CHUNK;

    // ---- stage obs chunk -> f16 pairs in LDS (round-0 verbatim) ----
    if (tid < 128) {
      int t = tid >> 4, fq = tid & 15;
      f4 v = *(const f4*)(obs_b + (size_t)(t0 + t) * NF + fq * 4);
      xbuf[t * 32 + fq * 2] = h2{(_Float16)v[0], (_Float16)v[1]};
      xbuf[t * 32 + fq * 2 + 1] = h2{(_Float16)v[2], (_Float16)v[3]};
    }
    __syncthreads();

    // ---- xg for rows tid and tid+512 (round-0 math, [t][u][4g] store) ----
#pragma unroll
    for (int rr = 0; rr < 2; ++rr) {
      const int row = tid + rr * 512;
      const float bias = rr ? bg1 : bg0;
      float acc[CHUNK];
#pragma unroll
      for (int t = 0; t < CHUNK; t++) acc[t] = bias;
      const h8* wrow = (const h8*)wih + row * 8;
#pragma unroll
      for (int jh = 0; jh < 2; jh++) {
        h8 w[4];
#pragma unroll
        for (int qq = 0; qq < 4; qq++) w[qq] = wrow[jh * 4 + qq];
#pragma unroll
        for (int t = 0; t < CHUNK; t++) {
#pragma unroll
          for (int qq = 0; qq < 4; qq++) {
            h8 xv = *(const h8*)&xbuf[t * 32 + jh * 16 + qq * 4];
            acc[t] = dot8(xv, w[qq], acc[t]);
          }
        }
      }
      const int g = row >> 8, uu = row & 255;
#pragma unroll
      for (int t = 0; t < CHUNK; t++)
        xg_l[(t * 256 + uu) * 4 + g] = (_Float16)acc[t];
    }
    __syncthreads();

    // ---- 8 recurrent LSTM steps, ONE barrier each; software-pipelined ----
    // Every ds_read is issued >= one dot-group (~128 issue cyc) before its
    // first consumer: hv rotates through a0-3/b0-3, LDS weights through
    // u0-3/v0-3. Same operands/order-of-accumulation as r4.
    for (int t = 0; t < CHUNK; t++) {
      const h8* hb8 =
          (const h8*)((const _Float16*)&hbuf[t & 1][jhalf * HHALF]);
      // issue: hv group A (j=0..3) + w(s=0)
      h8 a0 = hb8[0], a1 = hb8[1], a2 = hb8[2], a3 = hb8[3];
      h8 u0 = wlA[0 * NTHREADS], u1 = wlA[4 * NTHREADS];
      h8 u2 = wlB[0 * NTHREADS], u3 = wlB[4 * NTHREADS];
      h4 xg4 = *(const h4*)&xg_l[(t * 256 + q) * 4];
      float p0 = 0.f, p1 = 0.f, p2 = 0.f, p3 = 0.f;
      // s=0: issue w(s=1); consume a0 x u*
      h8 v0 = wlA[1 * NTHREADS], v1 = wlA[5 * NTHREADS];
      h8 v2 = wlB[1 * NTHREADS], v3 = wlB[5 * NTHREADS];
      p0 = dot8(a0, u0, p0); p1 = dot8(a0, u1, p1);
      p2 = dot8(a0, u2, p2); p3 = dot8(a0, u3, p3);
      // s=1: issue w(s=2); consume a1 x v*
      u0 = wlA[2 * NTHREADS]; u1 = wlA[6 * NTHREADS];
      u2 = wlB[2 * NTHREADS]; u3 = wlB[6 * NTHREADS];
      p0 = dot8(a1, v0, p0); p1 = dot8(a1, v1, p1);
      p2 = dot8(a1, v2, p2); p3 = dot8(a1, v3, p3);
      // s=2: issue w(s=3); consume a2 x u*
      v0 = wlA[3 * NTHREADS]; v1 = wlA[7 * NTHREADS];
      v2 = wlB[3 * NTHREADS]; v3 = wlB[7 * NTHREADS];
      p0 = dot8(a2, u0, p0); p1 = dot8(a2, u1, p1);
      p2 = dot8(a2, u2, p2); p3 = dot8(a2, u3, p3);
      // s=3: issue hv group B (j=4..7); consume a3 x v*
      h8 b0 = hb8[4], b1 = hb8[5], b2 = hb8[6], b3 = hb8[7];
      p0 = dot8(a3, v0, p0); p1 = dot8(a3, v1, p1);
      p2 = dot8(a3, v2, p2); p3 = dot8(a3, v3, p3);
      // jj=0..3: issue hv j=8..11; consume b* x wreg[0..3]
      a0 = hb8[8];
      p0 = dot8(b0, wreg[0], p0);  p1 = dot8(b0, wreg[12], p1);
      p2 = dot8(b0, wreg[24], p2); p3 = dot8(b0, wreg[36], p3);
      a1 = hb8[9];
      p0 = dot8(b1, wreg[1], p0);  p1 = dot8(b1, wreg[13], p1);
      p2 = dot8(b1, wreg[25], p2); p3 = dot8(b1, wreg[37], p3);
      a2 = hb8[10];
      p0 = dot8(b2, wreg[2], p0);  p1 = dot8(b2, wreg[14], p1);
      p2 = dot8(b2, wreg[26], p2); p3 = dot8(b2, wreg[38], p3);
      a3 = hb8[11];
      p0 = dot8(b3, wreg[3], p0);  p1 = dot8(b3, wreg[15], p1);
      p2 = dot8(b3, wreg[27], p2); p3 = dot8(b3, wreg[39], p3);
      // jj=4..7: issue hv j=12..15; consume a* x wreg[4..7]
      b0 = hb8[12];
      p0 = dot8(a0, wreg[4], p0);  p1 = dot8(a0, wreg[16], p1);
      p2 = dot8(a0, wreg[28], p2); p3 = dot8(a0, wreg[40], p3);
      b1 = hb8[13];
      p0 = dot8(a1, wreg[5], p0);  p1 = dot8(a1, wreg[17], p1);
      p2 = dot8(a1, wreg[29], p2); p3 = dot8(a1, wreg[41], p3);
      b2 = hb8[14];
      p0 = dot8(a2, wreg[6], p0);  p1 = dot8(a2, wreg[18], p1);
      p2 = dot8(a2, wreg[30], p2); p3 = dot8(a2, wreg[42], p3);
      b3 = hb8[15];
      p0 = dot8(a3, wreg[7], p0);  p1 = dot8(a3, wreg[19], p1);
      p2 = dot8(a3, wreg[31], p2); p3 = dot8(a3, wreg[43], p3);
      // jj=8..11: consume b* x wreg[8..11]
      p0 = dot8(b0, wreg[8], p0);  p1 = dot8(b0, wreg[20], p1);
      p2 = dot8(b0, wreg[32], p2); p3 = dot8(b0, wreg[44], p3);
      p0 = dot8(b1, wreg[9], p0);  p1 = dot8(b1, wreg[21], p1);
      p2 = dot8(b1, wreg[33], p2); p3 = dot8(b1, wreg[45], p3);
      p0 = dot8(b2, wreg[10], p0); p1 = dot8(b2, wreg[22], p1);
      p2 = dot8(b2, wreg[34], p2); p3 = dot8(b2, wreg[46], p3);
      p0 = dot8(b3, wreg[11], p0); p1 = dot8(b3, wreg[23], p1);
      p2 = dot8(b3, wreg[35], p2); p3 = dot8(b3, wreg[47], p3);
      // xor-1 DPP butterfly: both lanes of the pair get all 4 full sums.
      p0 += qperm<0xB1>(p0);
      p1 += qperm<0xB1>(p1);
      p2 += qperm<0xB1>(p2);
      p3 += qperm<0xB1>(p3);
      float gi = sigmoidf_(p0 + (float)xg4[0]);
      float gf = sigmoidf_(p1 + (float)xg4[1]);
      float gg = tanhfast(p2 + (float)xg4[2]);
      float go = sigmoidf_(p3 + (float)xg4[3]);
      c_state = gf * c_state + gi * gg;
      float hval = go * tanhfast(c_state);
      if (jhalf == 0) {  // one lane per unit publishes
        _Float16 hh = (_Float16)hval;
        ((_Float16*)&hbuf[(t + 1) & 1][(q >> 7) * HHALF])[q & 127] = hh;
        ((_Float16*)hch)[t * NH + q] = hh;  // history for layer2
      }
      __syncthreads();  // h(t+1) visible; hbuf[t&1] free for step t+2's write
    }

    // ---- layer2: x2 = relu(h @ W2^T + b2); W2 row double-buffered ----
    {
      const int o = tid & 255;
      const int tb = (tid >> 8) * 4;  // 4 timesteps per thread
      float acc[4] = {b2v, b2v, b2v, b2v};
      const h8* wrow = (const h8*)w2w + o * 32;
      const h8* hs = (const h8*)hch + tb * 32;  // xv = hs[tt*32 + c*4 + qq]
      h8 wa[4], wb[4];
#pragma unroll
      for (int qq = 0; qq < 4; qq++) wa[qq] = wrow[qq];
#pragma unroll
      for (int cc = 0; cc < 4; cc++) {
        const int ce = 2 * cc, codd = 2 * cc + 1;
        const int cn = (2 * cc + 2 < 8) ? 2 * cc + 2 : 7;  // tail reread, harmless
#pragma unroll
        for (int qq = 0; qq < 4; qq++) wb[qq] = wrow[codd * 4 + qq];
#pragma unroll
        for (int tt = 0; tt < 4; tt++)
#pragma unroll
          for (int qq = 0; qq < 4; qq++)
            acc[tt] = dot8(hs[tt * 32 + ce * 4 + qq], wa[qq], acc[tt]);
#pragma unroll
        for (int qq = 0; qq < 4; qq++) wa[qq] = wrow[cn * 4 + qq];
#pragma unroll
        for (int tt = 0; tt < 4; tt++)
#pragma unroll
          for (int qq = 0; qq < 4; qq++)
            acc[tt] = dot8(hs[tt * 32 + codd * 4 + qq], wb[qq], acc[tt]);
      }
#pragma unroll
      for (int tt = 0; tt < 4; tt++)
        ((_Float16*)x2b)[(tb + tt) * NH + o] = (_Float16)fmaxf(acc[tt], 0.f);
    }
    __syncthreads();

    // ---- heads: 32 outputs x 8 timesteps on first 256 threads (verbatim) ----
    if (tid < 256) {
      const int tt = tid >> 5;
      const h8* wrow = (const h8*)wmh + oh * 32;
      float acc = 0.f;
#pragma unroll 4
      for (int c = 0; c < 32; c++) {
        h8 xv = *(const h8*)&x2b[tt * 128 + c * 4];
        acc = dot8(xv, wrow[c], acc);
      }
      acc += hbv;
      const size_t idx = ((size_t)b * NT + (t0 + tt)) * NA + (oh & 15);
      if (oh < NA) {
        out_means[idx] = acc;
      } else {
        float ls = fminf(fmaxf(acc, -20.f), 2.f);
        out_stds[idx] = fexp2(1.4426950408889634f * ls);
      }
    }
    // no trailing barrier: next chunk's first write to x2b (its layer2) is
    // separated from these reads by the staging/xg/step barriers.
  }
}

extern "C" void kernel_launch(void* const* d_in, const int* in_sizes, int n_in,
                              void* d_out, int out_size, void* d_ws, size_t ws_size,
                              hipStream_t stream) {
  const float* obs = (const float*)d_in[0];
  const float* Wih = (const float*)d_in[1];
  const float* Whh = (const float*)d_in[2];
  const float* bih = (const float*)d_in[3];
  const float* bhh = (const float*)d_in[4];
  const float* W2 = (const float*)d_in[5];
  const float* b2 = (const float*)d_in[6];
  const float* Wm = (const float*)d_in[7];
  const float* bm = (const float*)d_in[8];
  const float* Ws = (const float*)d_in[9];
  const float* bs = (const float*)d_in[10];

  char* ws = (char*)d_ws;
  h2* whh = (h2*)(ws + 0);            // 512 KB
  h2* wih = (h2*)(ws + 524288);       // 128 KB
  h2* w2w = (h2*)(ws + 655360);       // 128 KB
  h2* wmh = (h2*)(ws + 786432);       // 16 KB
  float* bg = (float*)(ws + 802816);  // 4 KB

  prep_kernel<<<512, 256, 0, stream>>>(Wih, Whh, bih, bhh, W2, Wm, Ws,
                                       whh, wih, w2w, wmh, bg);
  actor_kernel<<<NB, NTHREADS, 0, stream>>>(obs, whh, wih, w2w, wmh, bg, b2, bm,
                                            bs, (float*)d_out);
}